// Round 1
// baseline (137.319 us; speedup 1.0000x reference)
//
#include <hip/hip_runtime.h>
#include <hip/hip_bf16.h>

// PGExplainer edge-MLP:
//   logits[e] = relu(concat(emb[src], emb[dst]) @ W1 + b1) @ W2 + b2
// Restructured: A[n] = emb[n] @ W1[:64] + b1 ; B[n] = emb[n] @ W1[64:]
//   logits[e] = relu(A[src]+B[dst]) . W2 + b2
// A,B stored interleaved per node as bf16: AB[n*128 + j] (j<64 = A, j>=64 = B).

__device__ __forceinline__ float bf2f(unsigned short u) {
    union { unsigned int i; float f; } v;
    v.i = ((unsigned int)u) << 16;
    return v.f;
}
__device__ __forceinline__ unsigned short f2bf(float f) {
    union { float f; unsigned int i; } v;
    v.f = f;
    unsigned int r = v.i + 0x7fffu + ((v.i >> 16) & 1u);  // RNE
    return (unsigned short)(r >> 16);
}

// One wave per node. W1 held in 128 VGPRs (fully unrolled k-loop -> static
// indexing, stays in registers). emb[n][k] broadcast across the wave via shfl.
__global__ __launch_bounds__(256) void precompute_ab(
    const float* __restrict__ emb, const float* __restrict__ W1,
    const float* __restrict__ b1, unsigned short* __restrict__ AB,
    int nNodes, int totalWaves)
{
    const int lane = threadIdx.x & 63;
    const int waveId = blockIdx.x * (blockDim.x >> 6) + (threadIdx.x >> 6);

    float w1a[64], w1b[64];
#pragma unroll
    for (int k = 0; k < 64; ++k) {
        w1a[k] = W1[k * 64 + lane];          // W1[k][lane],    k in [0,64)
        w1b[k] = W1[(64 + k) * 64 + lane];   // W1[64+k][lane]
    }
    const float bias = b1[lane];

    for (int n = waveId; n < nNodes; n += totalWaves) {
        const float e = emb[n * 64 + lane];
        float accA = bias;
        float accB = 0.f;
#pragma unroll
        for (int k = 0; k < 64; ++k) {
            const float ek = __shfl(e, k, 64);
            accA = fmaf(ek, w1a[k], accA);
            accB = fmaf(ek, w1b[k], accB);
        }
        AB[n * 128 + lane]      = f2bf(accA);
        AB[n * 128 + 64 + lane] = f2bf(accB);
    }
}

// 16 lanes per edge, 4 edges per wave. Each lane handles 4 of the 64 hidden
// units: bf16x4 slice of A[src] and B[dst] (group of 16 lanes = 128B
// contiguous segment -> coalesced gather), then shfl_xor tree-reduce.
__global__ __launch_bounds__(256) void edge_mlp(
    const int* __restrict__ ei, const unsigned short* __restrict__ AB,
    const float* __restrict__ W2, const float* __restrict__ b2,
    float* __restrict__ out, int nEdges, int totalWaves)
{
    const int lane = threadIdx.x & 63;
    const int sub  = lane & 15;   // hidden-chunk index within edge
    const int grp  = lane >> 4;   // which of the wave's 4 edges
    const int waveId = blockIdx.x * (blockDim.x >> 6) + (threadIdx.x >> 6);

    const float4 w2v = *reinterpret_cast<const float4*>(W2 + sub * 4);
    const float  b2s = b2[0];
    const int stride = totalWaves * 4;

    for (int e0 = waveId * 4; e0 < nEdges; e0 += stride) {
        const int e = e0 + grp;
        const bool valid = (e < nEdges);
        const int ec = valid ? e : 0;

        const int src = ei[ec];
        const int dst = ei[nEdges + ec];

        const ushort4 a4 = *reinterpret_cast<const ushort4*>(AB + src * 128 + sub * 4);
        const ushort4 b4 = *reinterpret_cast<const ushort4*>(AB + dst * 128 + 64 + sub * 4);

        const float h0 = fmaxf(bf2f(a4.x) + bf2f(b4.x), 0.f);
        const float h1 = fmaxf(bf2f(a4.y) + bf2f(b4.y), 0.f);
        const float h2 = fmaxf(bf2f(a4.z) + bf2f(b4.z), 0.f);
        const float h3 = fmaxf(bf2f(a4.w) + bf2f(b4.w), 0.f);

        float p = fmaf(h0, w2v.x, fmaf(h1, w2v.y, fmaf(h2, w2v.z, h3 * w2v.w)));

        // reduce over the 16 lanes of this edge
        p += __shfl_xor(p, 1, 64);
        p += __shfl_xor(p, 2, 64);
        p += __shfl_xor(p, 4, 64);
        p += __shfl_xor(p, 8, 64);

        if (valid && sub == 0) out[e] = p + b2s;
    }
}

extern "C" void kernel_launch(void* const* d_in, const int* in_sizes, int n_in,
                              void* d_out, int out_size, void* d_ws, size_t ws_size,
                              hipStream_t stream) {
    const float* emb = (const float*)d_in[0];
    const int*   ei  = (const int*)d_in[1];
    const float* W1  = (const float*)d_in[2];
    const float* b1  = (const float*)d_in[3];
    const float* W2  = (const float*)d_in[4];
    const float* b2  = (const float*)d_in[5];
    float* out = (float*)d_out;
    unsigned short* AB = (unsigned short*)d_ws;   // nNodes*128 bf16 = 12.8 MB

    const int nNodes = in_sizes[0] / 64;   // 50000
    const int nEdges = in_sizes[1] / 2;    // 800000

    {
        const int blocks = 1024;                        // 4096 waves, ~12 nodes each
        precompute_ab<<<blocks, 256, 0, stream>>>(emb, W1, b1, AB, nNodes, blocks * 4);
    }
    {
        const int blocks = 2048;                        // 8192 waves, 4 edges/iter
        edge_mlp<<<blocks, 256, 0, stream>>>(ei, AB, W2, b2, out, nEdges, blocks * 4);
    }
}

// Round 2
// 120.848 us; speedup vs baseline: 1.1363x; 1.1363x over previous
//
#include <hip/hip_runtime.h>
#include <hip/hip_bf16.h>

// PGExplainer edge-MLP:
//   logits[e] = relu(concat(emb[src], emb[dst]) @ W1 + b1) @ W2 + b2
// Restructured: A[n] = emb[n] @ W1[:64] + b1 ; B[n] = emb[n] @ W1[64:]
//   logits[e] = relu(A[src]+B[dst]) . W2 + b2
// A,B stored per node as bf16: AB[n*128 + j] (j<64 = A, j>=64 = B).
//
// R1 changes vs R0:
//  - precompute: __shfl (ds_bpermute, ~120cy latency each, serialized) ->
//    __builtin_amdgcn_readlane (VALU pipe). + prefetch next node's emb.
//  - edge: 8 lanes/edge (16B uint4 gathers), bf16 unpack via shift/and,
//    3-step ds_swizzle reduce, unroll 2.

__device__ __forceinline__ unsigned short f2bf(float f) {
    union { float f; unsigned int i; } v;
    v.f = f;
    unsigned int r = v.i + 0x7fffu + ((v.i >> 16) & 1u);  // RNE
    return (unsigned short)(r >> 16);
}

// One wave per node. W1 held in 128 VGPRs (fully unrolled -> static indexing).
// emb[n][k] broadcast via v_readlane (VALU, no LDS latency).
__global__ __launch_bounds__(256) void precompute_ab(
    const float* __restrict__ emb, const float* __restrict__ W1,
    const float* __restrict__ b1, unsigned short* __restrict__ AB,
    int nNodes, int totalWaves)
{
    const int lane = threadIdx.x & 63;
    const int waveId = blockIdx.x * (blockDim.x >> 6) + (threadIdx.x >> 6);

    float w1a[64], w1b[64];
#pragma unroll
    for (int k = 0; k < 64; ++k) {
        w1a[k] = W1[k * 64 + lane];          // W1[k][lane]
        w1b[k] = W1[(64 + k) * 64 + lane];   // W1[64+k][lane]
    }
    const float bias = b1[lane];

    int n = waveId;
    if (n >= nNodes) return;
    float e = emb[(size_t)n * 64 + lane];

    while (true) {
        const int n2 = n + totalWaves;
        float e_next = 0.f;
        if (n2 < nNodes) e_next = emb[(size_t)n2 * 64 + lane];  // prefetch

        float accA = bias;
        float accB = 0.f;
#pragma unroll
        for (int k = 0; k < 64; ++k) {
            const float ek = __int_as_float(
                __builtin_amdgcn_readlane(__float_as_int(e), k));
            accA = fmaf(ek, w1a[k], accA);
            accB = fmaf(ek, w1b[k], accB);
        }
        AB[(size_t)n * 128 + lane]      = f2bf(accA);
        AB[(size_t)n * 128 + 64 + lane] = f2bf(accB);

        if (n2 >= nNodes) break;
        n = n2;
        e = e_next;
    }
}

// 8 lanes per edge, 8 edges per wave. Each lane: 8 hidden units via one
// uint4 (16B = 8 bf16) load per operand; 8-lane groups read 128B contiguous
// segments -> fully coalesced gather. Reduce: 3 static ds_swizzle xor steps.
__global__ __launch_bounds__(256) void edge_mlp(
    const int* __restrict__ ei, const unsigned int* __restrict__ AB,
    const float* __restrict__ W2, const float* __restrict__ b2,
    float* __restrict__ out, int nEdges, int totalWaves)
{
    const int lane = threadIdx.x & 63;
    const int sub  = lane & 7;    // hidden-chunk (8 units) within edge
    const int grp  = lane >> 3;   // which of the wave's 8 edges
    const int waveId = blockIdx.x * (blockDim.x >> 6) + (threadIdx.x >> 6);

    float w2v[8];
#pragma unroll
    for (int j = 0; j < 8; ++j) w2v[j] = W2[sub * 8 + j];
    const float b2s = b2[0];
    const int stride = totalWaves * 8;

#pragma unroll 2
    for (int base = waveId * 8; base < nEdges; base += stride) {
        const int e = base + grp;
        const bool valid = (e < nEdges);
        const int ec = valid ? e : 0;

        const int src = ei[ec];
        const int dst = ei[nEdges + ec];

        // A-slice: uints [src*64 + sub*4 ..], B-slice: [dst*64 + 32 + sub*4 ..]
        const uint4 ua = *reinterpret_cast<const uint4*>(AB + (size_t)src * 64 + sub * 4);
        const uint4 ub = *reinterpret_cast<const uint4*>(AB + (size_t)dst * 64 + 32 + sub * 4);

        float p = 0.f;
        const unsigned int au[4] = {ua.x, ua.y, ua.z, ua.w};
        const unsigned int bu[4] = {ub.x, ub.y, ub.z, ub.w};
#pragma unroll
        for (int i = 0; i < 4; ++i) {
            const float alo = __int_as_float((int)(au[i] << 16));
            const float ahi = __int_as_float((int)(au[i] & 0xffff0000u));
            const float blo = __int_as_float((int)(bu[i] << 16));
            const float bhi = __int_as_float((int)(bu[i] & 0xffff0000u));
            const float h0 = fmaxf(alo + blo, 0.f);
            const float h1 = fmaxf(ahi + bhi, 0.f);
            p = fmaf(h0, w2v[2 * i], p);
            p = fmaf(h1, w2v[2 * i + 1], p);
        }

        // reduce over the 8 lanes of this edge (static swizzle, xor 1/2/4)
        p += __int_as_float(__builtin_amdgcn_ds_swizzle(__float_as_int(p), 0x041F));
        p += __int_as_float(__builtin_amdgcn_ds_swizzle(__float_as_int(p), 0x081F));
        p += __int_as_float(__builtin_amdgcn_ds_swizzle(__float_as_int(p), 0x101F));

        if (valid && sub == 0) out[e] = p + b2s;
    }
}

extern "C" void kernel_launch(void* const* d_in, const int* in_sizes, int n_in,
                              void* d_out, int out_size, void* d_ws, size_t ws_size,
                              hipStream_t stream) {
    const float* emb = (const float*)d_in[0];
    const int*   ei  = (const int*)d_in[1];
    const float* W1  = (const float*)d_in[2];
    const float* b1  = (const float*)d_in[3];
    const float* W2  = (const float*)d_in[4];
    const float* b2  = (const float*)d_in[5];
    float* out = (float*)d_out;
    unsigned short* AB = (unsigned short*)d_ws;   // nNodes*128 bf16 = 12.8 MB

    const int nNodes = in_sizes[0] / 64;   // 50000
    const int nEdges = in_sizes[1] / 2;    // 800000

    {
        // ~150 VGPR -> 3 waves/SIMD; 768 blocks = 3072 waves = exact residency
        const int blocks = 768;
        precompute_ab<<<blocks, 256, 0, stream>>>(emb, W1, b1, AB, nNodes, blocks * 4);
    }
    {
        // small VGPR -> 8 waves/SIMD; 2048 blocks = 8192 waves = full residency
        const int blocks = 2048;
        edge_mlp<<<blocks, 256, 0, stream>>>(ei, (const unsigned int*)AB, W2, b2,
                                             out, nEdges, blocks * 4);
    }
}